// Round 5
// baseline (206.343 us; speedup 1.0000x reference)
//
#include <hip/hip_runtime.h>
#include <cmath>

#define HH 512
#define WW 512
#define TW 32
#define TH 32
#define INH 42          /* TH + 10 halo rows */
#define HPS 36          /* hp row stride in dwords (mult of 4) */
#define C1F 0.0001f
#define C2F 0.0009f

struct GaussW { float w[11]; };

__global__ __launch_bounds__(256) void ssim_tile_kernel(
    const float* __restrict__ pred, const float* __restrict__ targ,
    float* __restrict__ partial, GaussW gw)
{
    // 4 fields: mu1-h, mu2-h, (p^2+t^2)-h, (p*t)-h   -> 24.2 KB
    __shared__ __align__(16) float hp[4][INH][HPS];
    __shared__ float wred[4];

    const int tid = threadIdx.x;
    const int bx = blockIdx.x, by = blockIdx.y, bz = blockIdx.z;
    const int gx0 = bx * TW;
    const int gy0 = by * TH - 5;
    const size_t plane = (size_t)bz * (size_t)(HH * WW);

    const bool xinterior = (bx > 0) && (bx < (WW / TW) - 1);

    // ---- Phase B: horizontal Gaussian directly from global memory ----
    // 336 tasks: 42 rows x 8 col-groups, each computes 4 output cols.
    if (xinterior) {
        for (int i = tid; i < INH * 8; i += 256) {
            int r = i >> 3;
            int c0 = (i & 7) << 2;
            int gr = gy0 + r;
            // p[m]/t[m] hold input col c0-6+m, m=0..15 (need m=1..14)
            float p[16], t[16];
            if ((unsigned)gr < (unsigned)HH) {
                const float* prow = pred + plane + (size_t)gr * WW + (gx0 + c0 - 6);
                const float* trow = targ + plane + (size_t)gr * WW + (gx0 + c0 - 6);
                *(float2*)&p[0]  = *(const float2*)(prow);
                *(float4*)&p[2]  = *(const float4*)(prow + 2);
                *(float4*)&p[6]  = *(const float4*)(prow + 6);
                *(float4*)&p[10] = *(const float4*)(prow + 10);
                *(float2*)&p[14] = *(const float2*)(prow + 14);
                *(float2*)&t[0]  = *(const float2*)(trow);
                *(float4*)&t[2]  = *(const float4*)(trow + 2);
                *(float4*)&t[6]  = *(const float4*)(trow + 6);
                *(float4*)&t[10] = *(const float4*)(trow + 10);
                *(float2*)&t[14] = *(const float2*)(trow + 14);
            } else {
                #pragma unroll
                for (int m = 0; m < 16; m++) { p[m] = 0.f; t[m] = 0.f; }
            }

            float sq[14], pt[14];
            #pragma unroll
            for (int m = 0; m < 14; m++) {
                float pv = p[m + 1], tv = t[m + 1];
                sq[m] = pv * pv + tv * tv;
                pt[m] = pv * tv;
            }

            float s1[4] = {0,0,0,0}, s2[4] = {0,0,0,0};
            float s3[4] = {0,0,0,0}, s4[4] = {0,0,0,0};
            #pragma unroll
            for (int k = 0; k < 11; k++) {
                float wk = gw.w[k];
                #pragma unroll
                for (int o = 0; o < 4; o++) {
                    s1[o] += wk * p[o + k + 1];
                    s2[o] += wk * t[o + k + 1];
                    s3[o] += wk * sq[o + k];
                    s4[o] += wk * pt[o + k];
                }
            }
            *(float4*)&hp[0][r][c0] = make_float4(s1[0], s1[1], s1[2], s1[3]);
            *(float4*)&hp[1][r][c0] = make_float4(s2[0], s2[1], s2[2], s2[3]);
            *(float4*)&hp[2][r][c0] = make_float4(s3[0], s3[1], s3[2], s3[3]);
            *(float4*)&hp[3][r][c0] = make_float4(s4[0], s4[1], s4[2], s4[3]);
        }
    } else {
        for (int i = tid; i < INH * 8; i += 256) {
            int r = i >> 3;
            int c0 = (i & 7) << 2;
            int gr = gy0 + r;
            float p[14], t[14];
            if ((unsigned)gr < (unsigned)HH) {
                const size_t rb = plane + (size_t)gr * WW;
                int cbase = gx0 + c0 - 5;
                #pragma unroll
                for (int m = 0; m < 14; m++) {
                    int gc = cbase + m;
                    int cc = min(max(gc, 0), WW - 1);
                    bool in = (unsigned)gc < (unsigned)WW;
                    float pv = pred[rb + cc];
                    float tv = targ[rb + cc];
                    p[m] = in ? pv : 0.f;
                    t[m] = in ? tv : 0.f;
                }
            } else {
                #pragma unroll
                for (int m = 0; m < 14; m++) { p[m] = 0.f; t[m] = 0.f; }
            }

            float s1[4] = {0,0,0,0}, s2[4] = {0,0,0,0};
            float s3[4] = {0,0,0,0}, s4[4] = {0,0,0,0};
            #pragma unroll
            for (int k = 0; k < 11; k++) {
                float wk = gw.w[k];
                #pragma unroll
                for (int o = 0; o < 4; o++) {
                    float pv = p[o + k], tv = t[o + k];
                    float wp = wk * pv, wt = wk * tv;
                    s1[o] += wp;
                    s2[o] += wt;
                    s3[o] += wp * pv + wt * tv;
                    s4[o] += wp * tv;
                }
            }
            *(float4*)&hp[0][r][c0] = make_float4(s1[0], s1[1], s1[2], s1[3]);
            *(float4*)&hp[1][r][c0] = make_float4(s2[0], s2[1], s2[2], s2[3]);
            *(float4*)&hp[2][r][c0] = make_float4(s3[0], s3[1], s3[2], s3[3]);
            *(float4*)&hp[3][r][c0] = make_float4(s4[0], s4[1], s4[2], s4[3]);
        }
    }
    __syncthreads();

    // ---- Phase C: vertical Gaussian, 4 rows x 1 col per lane + SSIM ----
    float local = 0.f;
    {
        int c  = tid & 31;          // 0..31
        int r0 = (tid >> 5) << 2;   // 0..28

        float acc[4][4];
        #pragma unroll
        for (int f = 0; f < 4; f++)
            #pragma unroll
            for (int rr = 0; rr < 4; rr++)
                acc[f][rr] = 0.f;

        #pragma unroll
        for (int jj = 0; jj < 14; jj++) {
            float v[4];
            #pragma unroll
            for (int f = 0; f < 4; f++)
                v[f] = hp[f][r0 + jj][c];
            #pragma unroll
            for (int rr = 0; rr < 4; rr++) {
                int k = jj - rr;
                if (k >= 0 && k < 11) {
                    float wk = gw.w[k];
                    #pragma unroll
                    for (int f = 0; f < 4; f++)
                        acc[f][rr] += wk * v[f];
                }
            }
        }

        #pragma unroll
        for (int rr = 0; rr < 4; rr++) {
            float m1 = acc[0][rr], m2 = acc[1][rr];
            float e3 = acc[2][rr], e12 = acc[3][rr];
            float m1s = m1 * m1, m2s = m2 * m2, m12 = m1 * m2;
            float num = (2.f * m12 + C1F) * (2.f * (e12 - m12) + C2F);
            float den = (m1s + m2s + C1F) * (e3 - m1s - m2s + C2F);
            local += num * __builtin_amdgcn_rcpf(den);
        }
    }

    // ---- block reduction ----
    #pragma unroll
    for (int off = 32; off > 0; off >>= 1)
        local += __shfl_down(local, off, 64);
    int lane = tid & 63, wid = tid >> 6;
    if (lane == 0) wred[wid] = local;
    __syncthreads();
    if (tid == 0) {
        int bid = (bz * gridDim.y + by) * gridDim.x + bx;
        partial[bid] = wred[0] + wred[1] + wred[2] + wred[3];
    }
}

__global__ __launch_bounds__(256) void ssim_finalize_kernel(
    const float* __restrict__ partial, int n, float inv_count,
    float* __restrict__ out)
{
    __shared__ float sm[4];
    float s = 0.f;
    for (int i = threadIdx.x; i < n; i += 256)
        s += partial[i];
    #pragma unroll
    for (int off = 32; off > 0; off >>= 1)
        s += __shfl_down(s, off, 64);
    int lane = threadIdx.x & 63, wid = threadIdx.x >> 6;
    if (lane == 0) sm[wid] = s;
    __syncthreads();
    if (threadIdx.x == 0)
        out[0] = 1.0f - (sm[0] + sm[1] + sm[2] + sm[3]) * inv_count;
}

extern "C" void kernel_launch(void* const* d_in, const int* in_sizes, int n_in,
                              void* d_out, int out_size, void* d_ws, size_t ws_size,
                              hipStream_t stream)
{
    const float* pred = (const float*)d_in[0];
    const float* targ = (const float*)d_in[1];
    float* out = (float*)d_out;
    float* partial = (float*)d_ws;

    const int total = in_sizes[0];                 // 16*3*512*512 = 12582912
    const int nplanes = total / (HH * WW);         // 48

    GaussW gw;
    double g[11], s = 0.0;
    for (int i = 0; i < 11; i++) {
        double d = (double)(i - 5);
        g[i] = exp(-d * d / 4.5);
        s += g[i];
    }
    for (int i = 0; i < 11; i++) gw.w[i] = (float)(g[i] / s);

    dim3 grid(WW / TW, HH / TH, nplanes);          // 16 x 16 x 48 = 12288 blocks
    ssim_tile_kernel<<<grid, 256, 0, stream>>>(pred, targ, partial, gw);

    const int nblocks = (WW / TW) * (HH / TH) * nplanes;
    const float inv_count = 1.0f / (float)total;
    ssim_finalize_kernel<<<1, 256, 0, stream>>>(partial, nblocks, inv_count, out);
}